// Round 11
// baseline (164.502 us; speedup 1.0000x reference)
//
#include <hip/hip_runtime.h>

#define NCLS 19
#define HWSZ (512*1024)
#define NB   8
#define CHUNK 2048            // pixels per block
#define TPX   128             // pixels per staged tile
#define NT    (CHUNK/TPX)     // 16 tiles
#define EPSM  1e-6f
#define EPSPD 1e-6f

#define ROWP 20
#define COLP 32
#define SUMS_ELEMS (NB*2*ROWP*COLP)
#define F4T  (NCLS*TPX/4)     // 608 float4 granules per tensor-tile

typedef short bf16x8 __attribute__((ext_vector_type(8)));
typedef float f32x16 __attribute__((ext_vector_type(16)));
typedef unsigned uint4v __attribute__((ext_vector_type(4)));

// ---------- staging in NAMED registers, 2 sets (depth-2 prefetch) ----------
#define SG_DECL(set) float4 s##set##0, s##set##1, s##set##2, \
                            t##set##0, t##set##1, t##set##2;

// granule g within 128-px row: 0..31.  st=g>>2 (K-step), kg=(g>>1)&1, p=g&1
#define SG_INIT(j) { int f = tid + (j)*256; if ((j) == 2 && f >= F4T) f = F4T - 1; \
    const int row_ = f >> 5, g_ = f & 31;                                          \
    const int blk_ = ((g_ >> 2) << 1) | (g_ & 1);          /* st*2 + p  */         \
    const int slot_ = (((g_ >> 1) & 1) * 20) + row_;       /* kg*20+row */         \
    widx##j = blk_ * 40 + (slot_ ^ (blk_ & 7));                                    \
    goff##j = ((long)(n * NCLS + row_)) * HWSZ + chunk0 + (g_ << 2); }

#define SG_LOAD(set, j, tt) { const long o_ = goff##j + (long)(tt) * TPX; \
    s##set##j = *(const float4*)(S + o_);                                 \
    t##set##j = *(const float4*)(T + o_); }

#define SG_LOADS(set, tt) SG_LOAD(set,0,tt) SG_LOAD(set,1,tt) SG_LOAD(set,2,tt)

#define SG_WRITE(set, j) { Sb4[widx##j] = s##set##j; Tb4[widx##j] = t##set##j; }
#define SG_WRITES(set) SG_WRITE(set,0) SG_WRITE(set,1) SG_WRITE(set,2)

// fp32 -> packed bf16 hi / lo (exact split; hi = truncation, lo = remainder)
#define CVT(pA, pB, HI, LO) {                                                      \
    const unsigned uA = __builtin_bit_cast(unsigned, pA);                          \
    const unsigned uB = __builtin_bit_cast(unsigned, pB);                          \
    HI = __builtin_amdgcn_perm(uB, uA, 0x07060302u);                               \
    const float fa = (pA) - __builtin_bit_cast(float, uA & 0xFFFF0000u);           \
    const float fb = (pB) - __builtin_bit_cast(float, uB & 0xFFFF0000u);           \
    LO = __builtin_amdgcn_perm(__builtin_bit_cast(unsigned, fb),                   \
                               __builtin_bit_cast(unsigned, fa), 0x07060302u); }

#define BBIT(word, sh, ei) { const unsigned lb_ = ((word) >> (sh)) & 255u;         \
    B[ei] = (lb_ == ur) ? (short)0x3F80 : (short)0; }

#define COMPUTE_TILE(t_) {                                                          \
    _Pragma("unroll")                                                               \
    for (int i = 0; i < 4; ++i) {                                                   \
        const uint2 pk = *(const uint2*)(labP + (t_) * TPX + i * 16);               \
        const float4 d0 = xb4[ra[(2*i) & 7]     + (2*i) * 40];                      \
        const float4 d1 = xb4[ra[(2*i+1) & 7]   + (2*i+1) * 40];                    \
        bf16x8 B;                                                                   \
        BBIT(pk.x, 0, 0) BBIT(pk.x, 8, 1) BBIT(pk.x, 16, 2) BBIT(pk.x, 24, 3)      \
        BBIT(pk.y, 0, 4) BBIT(pk.y, 8, 5) BBIT(pk.y, 16, 6) BBIT(pk.y, 24, 7)      \
        unsigned h0, h1, h2, h3, l0_, l1_, l2_, l3_;                                \
        CVT(d0.x, d0.y, h0, l0_)  CVT(d0.z, d0.w, h1, l1_)                          \
        CVT(d1.x, d1.y, h2, l2_)  CVT(d1.z, d1.w, h3, l3_)                          \
        const bf16x8 hi = __builtin_bit_cast(bf16x8, (uint4v){h0, h1, h2, h3});     \
        const bf16x8 lo = __builtin_bit_cast(bf16x8, (uint4v){l0_, l1_, l2_, l3_}); \
        acc = __builtin_amdgcn_mfma_f32_32x32x16_bf16(hi, B, acc, 0, 0, 0);         \
        acc = __builtin_amdgcn_mfma_f32_32x32x16_bf16(lo, B, acc, 0, 0, 0);         \
    } }

#define TILE(set, t_) {                                                             \
    if ((t_) > 0) __syncthreads();                                                  \
    SG_WRITES(set)                                                                  \
    __syncthreads();                                                                \
    if ((t_) + 2 < NT) { SG_LOADS(set, (t_) + 2) }                                  \
    COMPUTE_TILE(t_) }

__global__ __launch_bounds__(256, 3) void icl_sums(
    const float* __restrict__ S, const float* __restrict__ T,
    const int* __restrict__ gt, float* __restrict__ sums)
{
    __shared__ float4 Sb4[16 * 40];            // [blk 0..15][slot 0..39], swizzled
    __shared__ float4 Tb4[16 * 40];
    __shared__ unsigned char labU[CHUNK];      // labels as bytes
    __shared__ float red[2][ROWP][COLP];

    const int tid = threadIdx.x;
    const int n   = blockIdx.y;
    // bijective XCD swizzle: 256 chunks = 8 XCDs x 32; each XCD gets a
    // contiguous 32-chunk span (xcd = blockIdx.x % 8 under linear dispatch).
    const int bx  = ((blockIdx.x & 7) << 5) | (blockIdx.x >> 3);
    const long chunk0 = (long)bx * CHUNK;

    for (int i = tid; i < 2 * ROWP * COLP; i += 256) ((float*)red)[i] = 0.f;

    // prefill count row (slot kg*20+19) in every blk, both buffers; stagers only
    // write rows 0..18, so this persists across all tiles.
    if (tid < 64) {
        const int b = tid >> 2, kg_ = (tid >> 1) & 1, tb = tid & 1;
        const int idx = b * 40 + (((kg_ * 20) + 19) ^ (b & 7));
        (tb ? Tb4 : Sb4)[idx] = make_float4(1.f, 1.f, 1.f, 1.f);
    }

    // labels -> packed u8 in LDS (coalesced)
    {
        const int4* gp = (const int4*)(gt + (long)n * HWSZ + chunk0);
        const int4 a = gp[tid], b = gp[tid + 256];
        const unsigned p0 = (unsigned)a.x | ((unsigned)a.y << 8) |
                            ((unsigned)a.z << 16) | ((unsigned)a.w << 24);
        const unsigned p1 = (unsigned)b.x | ((unsigned)b.y << 8) |
                            ((unsigned)b.z << 16) | ((unsigned)b.w << 24);
        ((unsigned*)labU)[tid]       = p0;
        ((unsigned*)labU)[tid + 256] = p1;
    }

    int widx0, widx1, widx2;
    long goff0, goff1, goff2;
    SG_INIT(0) SG_INIT(1) SG_INIT(2)
    SG_DECL(A) SG_DECL(B)

    const int wave = tid >> 6, lane = tid & 63;
    const int r  = lane & 31;                   // A-row (channel) / B-col (class)
    const int kg = lane >> 5;                   // 8-px half of the 16-px K-step
    const bool isT = wave >= 2;
    const int  ph  = wave & 1;                  // 64-px half of the 128-px tile
    const unsigned ur = (unsigned)r;

    // A-read indices: idx = ph*320 + (2i+p)*40 + (sbase ^ (2i+p))
    const int sbase = kg * 20 + (r < 20 ? r : r - 12);   // r>=20: harmless dup rows
    int ra[8];
#pragma unroll
    for (int k = 0; k < 8; ++k) ra[k] = ph * 320 + (sbase ^ k);

    const float4* xb4 = isT ? Tb4 : Sb4;
    const unsigned char* labP = labU + ph * 64 + kg * 8;

    f32x16 acc = {0,0,0,0,0,0,0,0,0,0,0,0,0,0,0,0};

    SG_LOADS(A, 0)
    SG_LOADS(B, 1)

    TILE(A, 0)  TILE(B, 1)  TILE(A, 2)  TILE(B, 3)
    TILE(A, 4)  TILE(B, 5)  TILE(A, 6)  TILE(B, 7)
    TILE(A, 8)  TILE(B, 9)  TILE(A, 10) TILE(B, 11)
    TILE(A, 12) TILE(B, 13) TILE(A, 14) TILE(B, 15)

    // C/D layout: col = lane&31, row = (e&3) + 8*(e>>2) + 4*(lane>>5)
#pragma unroll
    for (int e = 0; e < 16; ++e) {
        const int row = (e & 3) + 8 * (e >> 2) + 4 * kg;
        if (row < ROWP) atomicAdd(&red[isT ? 1 : 0][row][r], acc[e]);
    }
    __syncthreads();

    float* gs = sums + (long)n * 2 * ROWP * COLP;
    for (int i = tid; i < 2 * ROWP * COLP; i += 256) {
        if ((i & 31) < NCLS) atomicAdd(&gs[i], ((const float*)red)[i]);
    }
}

__global__ __launch_bounds__(256) void icl_final(
    const float* __restrict__ sums, float* __restrict__ out)
{
    __shared__ float v[NB][2][NCLS][NCLS];   // [n][t][k][c]
    __shared__ float red2[256];
    const int tid = threadIdx.x;

    for (int i = tid; i < NB * 2 * NCLS * NCLS; i += 256) {
        const int c = i % NCLS;
        const int k = (i / NCLS) % NCLS;
        const int t = (i / (NCLS * NCLS)) % 2;
        const int n = i / (2 * NCLS * NCLS);
        const float cnt = sums[((n * 2 + 0) * ROWP + NCLS) * COLP + k];
        const float val = sums[((n * 2 + t) * ROWP + c) * COLP + k];
        v[n][t][k][c] = val * (1.f / (cnt + EPSM));
    }
    __syncthreads();

    float acc = 0.f;
    const int NPAIR = NCLS * (NCLS - 1) / 2;   // 171
    for (int i = tid; i < NB * NPAIR; i += 256) {
        const int n = i / NPAIR;
        int rem = i % NPAIR;
        int k1 = 0;
        while (rem >= NCLS - 1 - k1) { rem -= NCLS - 1 - k1; ++k1; }
        const int k2 = k1 + 1 + rem;
        float ss = 0.f, st = 0.f;
#pragma unroll
        for (int c = 0; c < NCLS; ++c) {
            const float ds = v[n][0][k1][c] - v[n][0][k2][c] + EPSPD;
            const float dt = v[n][1][k1][c] - v[n][1][k2][c] + EPSPD;
            ss = fmaf(ds, ds, ss);
            st = fmaf(dt, dt, st);
        }
        const float e = sqrtf(st) - sqrtf(ss);
        acc += 0.5f * e * e;
    }

    red2[tid] = acc;
    __syncthreads();
    for (int s = 128; s > 0; s >>= 1) {
        if (tid < s) red2[tid] += red2[tid + s];
        __syncthreads();
    }
    if (tid == 0) out[0] = 0.5f * red2[0] / (float)NB;
}

extern "C" void kernel_launch(void* const* d_in, const int* in_sizes, int n_in,
                              void* d_out, int out_size, void* d_ws, size_t ws_size,
                              hipStream_t stream) {
    const float* S  = (const float*)d_in[0];
    const float* T  = (const float*)d_in[1];
    const int*   gt = (const int*)d_in[2];

    float* sums = (float*)d_ws;
    hipMemsetAsync(d_ws, 0, SUMS_ELEMS * sizeof(float), stream);

    dim3 grid(HWSZ / CHUNK, NB);   // (256, 8) = 2048 blocks
    icl_sums<<<grid, 256, 0, stream>>>(S, T, gt, sums);
    icl_final<<<1, 256, 0, stream>>>(sums, (float*)d_out);
}

// Round 12
// 138.685 us; speedup vs baseline: 1.1862x; 1.1862x over previous
//
#include <hip/hip_runtime.h>

#define NCLS 19
#define HWSZ (512*1024)
#define NB   8
#define CHUNK 8192            // pixels per block (32 KB contiguous per stream)
#define TPX   128             // pixels per staged tile
#define NT    (CHUNK/TPX)     // 64 tiles
#define EPSM  1e-6f
#define EPSPD 1e-6f

#define ROWP 20
#define COLP 32
#define SUMS_ELEMS (NB*2*ROWP*COLP)
#define F4T  (NCLS*TPX/4)     // 608 float4 granules per tensor-tile

typedef short bf16x8 __attribute__((ext_vector_type(8)));
typedef float f32x16 __attribute__((ext_vector_type(16)));
typedef unsigned uint4v __attribute__((ext_vector_type(4)));

// ---------- staging in NAMED registers, 2 sets (depth-2 prefetch) ----------
#define SG_DECL(set) float4 s##set##0, s##set##1, s##set##2, \
                            t##set##0, t##set##1, t##set##2;

// granule g within 128-px row: 0..31.  st=g>>2 (K-step), kg=(g>>1)&1, p=g&1
#define SG_INIT(j) { int f = tid + (j)*256; if ((j) == 2 && f >= F4T) f = F4T - 1; \
    const int row_ = f >> 5, g_ = f & 31;                                          \
    const int blk_ = ((g_ >> 2) << 1) | (g_ & 1);          /* st*2 + p  */         \
    const int slot_ = (((g_ >> 1) & 1) * 20) + row_;       /* kg*20+row */         \
    widx##j = blk_ * 40 + (slot_ ^ (blk_ & 7));                                    \
    goff##j = ((long)(n * NCLS + row_)) * HWSZ + chunk0 + (g_ << 2); }

#define SG_LOAD(set, j, tt) { const long o_ = goff##j + (long)(tt) * TPX; \
    s##set##j = *(const float4*)(S + o_);                                 \
    t##set##j = *(const float4*)(T + o_); }

#define SG_LOADS(set, tt) SG_LOAD(set,0,tt) SG_LOAD(set,1,tt) SG_LOAD(set,2,tt)

#define SG_WRITE(set, j) { Sb4[widx##j] = s##set##j; Tb4[widx##j] = t##set##j; }
#define SG_WRITES(set) SG_WRITE(set,0) SG_WRITE(set,1) SG_WRITE(set,2)

// fp32 -> packed bf16 hi / lo (exact split; hi = truncation, lo = remainder)
#define CVT(pA, pB, HI, LO) {                                                      \
    const unsigned uA = __builtin_bit_cast(unsigned, pA);                          \
    const unsigned uB = __builtin_bit_cast(unsigned, pB);                          \
    HI = __builtin_amdgcn_perm(uB, uA, 0x07060302u);                               \
    const float fa = (pA) - __builtin_bit_cast(float, uA & 0xFFFF0000u);           \
    const float fb = (pB) - __builtin_bit_cast(float, uB & 0xFFFF0000u);           \
    LO = __builtin_amdgcn_perm(__builtin_bit_cast(unsigned, fb),                   \
                               __builtin_bit_cast(unsigned, fa), 0x07060302u); }

#define BBIT(word, sh, ei) { const unsigned lb_ = ((word) >> (sh)) & 255u;         \
    B[ei] = (lb_ == ur) ? (short)0x3F80 : (short)0; }

#define COMPUTE_TILE(t_) {                                                          \
    _Pragma("unroll")                                                               \
    for (int i = 0; i < 4; ++i) {                                                   \
        const uint2 pk = *(const uint2*)(labP + (t_) * TPX + i * 16);               \
        const float4 d0 = xb4[ra[(2*i) & 7]     + (2*i) * 40];                      \
        const float4 d1 = xb4[ra[(2*i+1) & 7]   + (2*i+1) * 40];                    \
        bf16x8 B;                                                                   \
        BBIT(pk.x, 0, 0) BBIT(pk.x, 8, 1) BBIT(pk.x, 16, 2) BBIT(pk.x, 24, 3)      \
        BBIT(pk.y, 0, 4) BBIT(pk.y, 8, 5) BBIT(pk.y, 16, 6) BBIT(pk.y, 24, 7)      \
        unsigned h0, h1, h2, h3, l0_, l1_, l2_, l3_;                                \
        CVT(d0.x, d0.y, h0, l0_)  CVT(d0.z, d0.w, h1, l1_)                          \
        CVT(d1.x, d1.y, h2, l2_)  CVT(d1.z, d1.w, h3, l3_)                          \
        const bf16x8 hi = __builtin_bit_cast(bf16x8, (uint4v){h0, h1, h2, h3});     \
        const bf16x8 lo = __builtin_bit_cast(bf16x8, (uint4v){l0_, l1_, l2_, l3_}); \
        acc = __builtin_amdgcn_mfma_f32_32x32x16_bf16(hi, B, acc, 0, 0, 0);         \
        acc = __builtin_amdgcn_mfma_f32_32x32x16_bf16(lo, B, acc, 0, 0, 0);         \
    } }

#define TILE(set, t_) {                                                             \
    if ((t_) > 0) __syncthreads();                                                  \
    SG_WRITES(set)                                                                  \
    __syncthreads();                                                                \
    if ((t_) + 2 < NT) { SG_LOADS(set, (t_) + 2) }                                  \
    COMPUTE_TILE(t_) }

__global__ __launch_bounds__(256, 3) void icl_sums(
    const float* __restrict__ S, const float* __restrict__ T,
    const int* __restrict__ gt, float* __restrict__ sums)
{
    __shared__ float4 Sb4[16 * 40];            // [blk 0..15][slot 0..39], swizzled
    __shared__ float4 Tb4[16 * 40];
    __shared__ unsigned char labU[CHUNK];      // labels as bytes (8 KB)
    __shared__ float red[2][ROWP][COLP];

    const int tid = threadIdx.x;
    const int n   = blockIdx.y;
    const long chunk0 = (long)blockIdx.x * CHUNK;

    for (int i = tid; i < 2 * ROWP * COLP; i += 256) ((float*)red)[i] = 0.f;

    // prefill count row (slot kg*20+19) in every blk, both buffers; stagers only
    // write rows 0..18, so this persists across all tiles.
    if (tid < 64) {
        const int b = tid >> 2, kg_ = (tid >> 1) & 1, tb = tid & 1;
        const int idx = b * 40 + (((kg_ * 20) + 19) ^ (b & 7));
        (tb ? Tb4 : Sb4)[idx] = make_float4(1.f, 1.f, 1.f, 1.f);
    }

    // labels -> packed u8 in LDS (coalesced)
    {
        const int4* gp = (const int4*)(gt + (long)n * HWSZ + chunk0);
#pragma unroll
        for (int i = 0; i < CHUNK / 4 / 256; ++i) {
            const int4 a = gp[tid + i * 256];
            ((unsigned*)labU)[tid + i * 256] =
                (unsigned)a.x | ((unsigned)a.y << 8) |
                ((unsigned)a.z << 16) | ((unsigned)a.w << 24);
        }
    }

    int widx0, widx1, widx2;
    long goff0, goff1, goff2;
    SG_INIT(0) SG_INIT(1) SG_INIT(2)
    SG_DECL(A) SG_DECL(B)

    const int wave = tid >> 6, lane = tid & 63;
    const int r  = lane & 31;                   // A-row (channel) / B-col (class)
    const int kg = lane >> 5;                   // 8-px half of the 16-px K-step
    const bool isT = wave >= 2;
    const int  ph  = wave & 1;                  // 64-px half of the 128-px tile
    const unsigned ur = (unsigned)r;

    // A-read indices: idx = ph*320 + (2i+p)*40 + (sbase ^ (2i+p))
    const int sbase = kg * 20 + (r < 20 ? r : r - 12);   // r>=20: harmless dup rows
    int ra[8];
#pragma unroll
    for (int k = 0; k < 8; ++k) ra[k] = ph * 320 + (sbase ^ k);

    const float4* xb4 = isT ? Tb4 : Sb4;
    const unsigned char* labP = labU + ph * 64 + kg * 8;

    f32x16 acc = {0,0,0,0,0,0,0,0,0,0,0,0,0,0,0,0};

    SG_LOADS(A, 0)
    SG_LOADS(B, 1)

    for (int t = 0; t < NT; t += 2) {
        TILE(A, t)
        TILE(B, t + 1)
    }

    // C/D layout: col = lane&31, row = (e&3) + 8*(e>>2) + 4*(lane>>5)
#pragma unroll
    for (int e = 0; e < 16; ++e) {
        const int row = (e & 3) + 8 * (e >> 2) + 4 * kg;
        if (row < ROWP) atomicAdd(&red[isT ? 1 : 0][row][r], acc[e]);
    }
    __syncthreads();

    float* gs = sums + (long)n * 2 * ROWP * COLP;
    for (int i = tid; i < 2 * ROWP * COLP; i += 256) {
        if ((i & 31) < NCLS) atomicAdd(&gs[i], ((const float*)red)[i]);
    }
}

__global__ __launch_bounds__(256) void icl_final(
    const float* __restrict__ sums, float* __restrict__ out)
{
    __shared__ float v[NB][2][NCLS][NCLS];   // [n][t][k][c]
    __shared__ float red2[256];
    const int tid = threadIdx.x;

    for (int i = tid; i < NB * 2 * NCLS * NCLS; i += 256) {
        const int c = i % NCLS;
        const int k = (i / NCLS) % NCLS;
        const int t = (i / (NCLS * NCLS)) % 2;
        const int n = i / (2 * NCLS * NCLS);
        const float cnt = sums[((n * 2 + 0) * ROWP + NCLS) * COLP + k];
        const float val = sums[((n * 2 + t) * ROWP + c) * COLP + k];
        v[n][t][k][c] = val * (1.f / (cnt + EPSM));
    }
    __syncthreads();

    float acc = 0.f;
    const int NPAIR = NCLS * (NCLS - 1) / 2;   // 171
    for (int i = tid; i < NB * NPAIR; i += 256) {
        const int n = i / NPAIR;
        int rem = i % NPAIR;
        int k1 = 0;
        while (rem >= NCLS - 1 - k1) { rem -= NCLS - 1 - k1; ++k1; }
        const int k2 = k1 + 1 + rem;
        float ss = 0.f, st = 0.f;
#pragma unroll
        for (int c = 0; c < NCLS; ++c) {
            const float ds = v[n][0][k1][c] - v[n][0][k2][c] + EPSPD;
            const float dt = v[n][1][k1][c] - v[n][1][k2][c] + EPSPD;
            ss = fmaf(ds, ds, ss);
            st = fmaf(dt, dt, st);
        }
        const float e = sqrtf(st) - sqrtf(ss);
        acc += 0.5f * e * e;
    }

    red2[tid] = acc;
    __syncthreads();
    for (int s = 128; s > 0; s >>= 1) {
        if (tid < s) red2[tid] += red2[tid + s];
        __syncthreads();
    }
    if (tid == 0) out[0] = 0.5f * red2[0] / (float)NB;
}

extern "C" void kernel_launch(void* const* d_in, const int* in_sizes, int n_in,
                              void* d_out, int out_size, void* d_ws, size_t ws_size,
                              hipStream_t stream) {
    const float* S  = (const float*)d_in[0];
    const float* T  = (const float*)d_in[1];
    const int*   gt = (const int*)d_in[2];

    float* sums = (float*)d_ws;
    hipMemsetAsync(d_ws, 0, SUMS_ELEMS * sizeof(float), stream);

    dim3 grid(HWSZ / CHUNK, NB);   // (64, 8) = 512 blocks, all co-resident
    icl_sums<<<grid, 256, 0, stream>>>(S, T, gt, sums);
    icl_final<<<1, 256, 0, stream>>>(sums, (float*)d_out);
}